// Round 1
// baseline (15094.872 us; speedup 1.0000x reference)
//
#include <hip/hip_runtime.h>

// MeshGNN: N=50000 nodes, E=600000 edges, IN=16, ED=4, H=128, L=4, OUT=3
// fp32 baseline. Key identity: h[src]@W == (h@W)[src]  -> first msg layer is a
// node GEMM (hw) + per-edge rank-4 edge_attr term. Heavy per-edge GEMM is only
// m2 = relu(m1 @ msg_w2 + b2), fused with gather + scatter-add (atomics).

#define TILE_M 64

// ---------------------------------------------------------------------------
// lin_in: h = relu(x @ Win + b)   [N,16] @ [16,128]
__global__ __launch_bounds__(128) void lin_in_kernel(
    const float* __restrict__ x, const float* __restrict__ W,
    const float* __restrict__ b, float* __restrict__ h, int N) {
  __shared__ float xs[16][16];
  int t = threadIdx.x;
  int n0 = blockIdx.x * 16;
  for (int i = t; i < 256; i += 128) {
    int r = i >> 4, c = i & 15;
    int n = n0 + r;
    xs[r][c] = (n < N) ? x[(size_t)n * 16 + c] : 0.f;
  }
  __syncthreads();
  float wcol[16];
#pragma unroll
  for (int k = 0; k < 16; ++k) wcol[k] = W[k * 128 + t];
  float bb = b[t];
  for (int i = 0; i < 16; ++i) {
    int n = n0 + i;
    if (n >= N) break;
    float s = bb;
#pragma unroll
    for (int k = 0; k < 16; ++k) s += xs[i][k] * wcol[k];
    h[(size_t)n * 128 + t] = fmaxf(s, 0.f);
  }
}

// ---------------------------------------------------------------------------
__global__ __launch_bounds__(256) void count_kernel(const int* __restrict__ dst,
                                                    float* __restrict__ cnt, int E) {
  int e = blockIdx.x * 256 + threadIdx.x;
  if (e < E) atomicAdd(&cnt[dst[e]], 1.0f);
}

// ---------------------------------------------------------------------------
// Generic node GEMM: C[M][128] = act( A1@W1 (+ A2*scale @ W2) + bias (+ res) )
// W layout row-major [K][128]. 128 threads, 64-row tile, 8x8 acc per thread.
__global__ __launch_bounds__(128) void node_gemm(
    const float* __restrict__ A1, const float* __restrict__ W1, int K1,
    const float* __restrict__ A2, const float* __restrict__ W2, int K2,
    const float* __restrict__ cnt,   // if non-null: scale A2 rows by 1/max(cnt,1)
    const float* __restrict__ bias, const float* __restrict__ res,
    float* __restrict__ C, int M, int do_relu) {
  __shared__ float As[64 * 32];     // swizzled A chunk
  __shared__ float Ws[32][132];     // padded W chunk
  int t = threadIdx.x;
  int m0 = blockIdx.x * TILE_M;
  int mb = (t >> 4) * 8;            // 8 row-groups
  int fb = (t & 15) * 8;            // 16 col-groups
  float acc[8][8] = {};

  for (int op = 0; op < 2; ++op) {
    const float* A = op ? A2 : A1;
    const float* W = op ? W2 : W1;
    int K = op ? K2 : K1;
    if (!A) continue;
    bool doScale = (op == 1) && (cnt != nullptr);
    for (int kc = 0; kc < K; kc += 32) {
      __syncthreads();
      // stage A chunk [64][32], XOR-swizzled at float4 granularity
#pragma unroll
      for (int i = 0; i < 4; ++i) {
        int id = t + i * 128;               // 0..511
        int row = id >> 3, c4 = id & 7;
        int m = m0 + row;
        float4 v = make_float4(0.f, 0.f, 0.f, 0.f);
        if (m < M) {
          v = *(const float4*)&A[(size_t)m * K + kc + c4 * 4];
          if (doScale) {
            float s = 1.f / fmaxf(cnt[m], 1.f);
            v.x *= s; v.y *= s; v.z *= s; v.w *= s;
          }
        }
        int phys = c4 ^ ((row >> 3) & 3);
        *(float4*)&As[row * 32 + phys * 4] = v;
      }
      // stage W chunk [32][128] -> [32][132]
#pragma unroll
      for (int i = 0; i < 8; ++i) {
        int id = t + i * 128;               // 0..1023
        int r = id >> 5, c4 = id & 31;
        *(float4*)&Ws[r][c4 * 4] = *(const float4*)&W[(size_t)(kc + r) * 128 + c4 * 4];
      }
      __syncthreads();
#pragma unroll
      for (int kk4 = 0; kk4 < 8; ++kk4) {
        float a[8][4];
        float w[4][8];
#pragma unroll
        for (int kkk = 0; kkk < 4; ++kkk) {
          *(float4*)&w[kkk][0] = *(const float4*)&Ws[kk4 * 4 + kkk][fb];
          *(float4*)&w[kkk][4] = *(const float4*)&Ws[kk4 * 4 + kkk][fb + 4];
        }
#pragma unroll
        for (int i = 0; i < 8; ++i) {
          int row = mb + i;
          int phys = kk4 ^ ((row >> 3) & 3);
          *(float4*)&a[i][0] = *(const float4*)&As[row * 32 + phys * 4];
        }
#pragma unroll
        for (int i = 0; i < 8; ++i)
#pragma unroll
          for (int j = 0; j < 8; ++j)
            acc[i][j] += a[i][0] * w[0][j] + a[i][1] * w[1][j] +
                         a[i][2] * w[2][j] + a[i][3] * w[3][j];
      }
    }
  }
  // epilogue
#pragma unroll
  for (int i = 0; i < 8; ++i) {
    int m = m0 + mb + i;
    if (m >= M) continue;
#pragma unroll
    for (int j = 0; j < 8; ++j) {
      float v = acc[i][j];
      if (bias) v += bias[fb + j];
      if (res) v += res[(size_t)m * 128 + fb + j];
      if (do_relu) v = fmaxf(v, 0.f);
      C[(size_t)m * 128 + fb + j] = v;
    }
  }
}

// ---------------------------------------------------------------------------
// Edge kernel: per 64-edge tile.
//   m1 = relu(hw[src] + ea @ Wea)           (hw already includes msg_b1)
//   m2 = relu(m1 @ W2 + b2)
//   atomicAdd(agg[dst], m2)   (skip zeros: relu sparsity halves atomics)
__global__ __launch_bounds__(128) void edge_kernel(
    const float* __restrict__ hw, const float* __restrict__ ea,
    const int* __restrict__ src, const int* __restrict__ dst,
    const float* __restrict__ W2,   // [128][128]
    const float* __restrict__ Wea,  // [4][128]
    const float* __restrict__ b2,   // [128]
    float* __restrict__ agg, int E) {
  __shared__ float m1s[64 * 128];   // swizzled (f4 idx ^ (e>>3)&3)
  __shared__ float Ws[32][132];
  __shared__ float WeaS[4][128];
  __shared__ float b2s[128];
  int t = threadIdx.x;
  int e0 = blockIdx.x * TILE_M;

  for (int i = t; i < 512; i += 128) WeaS[i >> 7][i & 127] = Wea[i];
  b2s[t] = b2[t];
  __syncthreads();

  // phase 1: thread t = feature j, loop edges
#pragma unroll 8
  for (int e = 0; e < 64; ++e) {
    int eg = e0 + e;
    float v = 0.f;
    if (eg < E) {
      int s = src[eg];
      v = hw[(size_t)s * 128 + t];
      float4 eav = *(const float4*)&ea[(size_t)eg * 4];
      v += eav.x * WeaS[0][t] + eav.y * WeaS[1][t] +
           eav.z * WeaS[2][t] + eav.w * WeaS[3][t];
      v = fmaxf(v, 0.f);
    }
    int phys4 = (t >> 2) ^ ((e >> 3) & 3);
    m1s[e * 128 + phys4 * 4 + (t & 3)] = v;
  }
  __syncthreads();

  // phase 2: m2 = m1 @ W2
  int mb = (t >> 4) * 8;
  int fb = (t & 15) * 8;
  float acc[8][8] = {};
  for (int kc = 0; kc < 128; kc += 32) {
#pragma unroll
    for (int i = 0; i < 8; ++i) {
      int id = t + i * 128;
      int r = id >> 5, c4 = id & 31;
      *(float4*)&Ws[r][c4 * 4] = *(const float4*)&W2[(size_t)(kc + r) * 128 + c4 * 4];
    }
    __syncthreads();
#pragma unroll
    for (int kk4 = 0; kk4 < 8; ++kk4) {
      float a[8][4];
      float w[4][8];
#pragma unroll
      for (int kkk = 0; kkk < 4; ++kkk) {
        *(float4*)&w[kkk][0] = *(const float4*)&Ws[kk4 * 4 + kkk][fb];
        *(float4*)&w[kkk][4] = *(const float4*)&Ws[kk4 * 4 + kkk][fb + 4];
      }
#pragma unroll
      for (int i = 0; i < 8; ++i) {
        int row = mb + i;
        int f4g = (kc >> 2) + kk4;
        int phys = f4g ^ ((row >> 3) & 3);
        *(float4*)&a[i][0] = *(const float4*)&m1s[row * 128 + phys * 4];
      }
#pragma unroll
      for (int i = 0; i < 8; ++i)
#pragma unroll
        for (int j = 0; j < 8; ++j)
          acc[i][j] += a[i][0] * w[0][j] + a[i][1] * w[1][j] +
                       a[i][2] * w[2][j] + a[i][3] * w[3][j];
    }
    __syncthreads();
  }

  // epilogue: bias + relu + atomic scatter
#pragma unroll
  for (int i = 0; i < 8; ++i) {
    int eg = e0 + mb + i;
    if (eg >= E) continue;
    int d = dst[eg];
    float* dest = &agg[(size_t)d * 128 + fb];
#pragma unroll
    for (int j = 0; j < 8; ++j) {
      float v = fmaxf(acc[i][j] + b2s[fb + j], 0.f);
      if (v > 0.f) atomicAdd(&dest[j], v);
    }
  }
}

// ---------------------------------------------------------------------------
// head stage 2: out = relu(o @ head_w2 + head_b2)   [N,128] @ [128,3]
__global__ __launch_bounds__(128) void head_out_kernel(
    const float* __restrict__ o, const float* __restrict__ w2,
    const float* __restrict__ b2, float* __restrict__ out, int N) {
  __shared__ float os[16][128];
  __shared__ float w2s[384];
  __shared__ float b2s[3];
  int t = threadIdx.x;
  for (int i = t; i < 384; i += 128) w2s[i] = w2[i];
  if (t < 3) b2s[t] = b2[t];
  int n0 = blockIdx.x * 16;
  for (int i = 0; i < 16; ++i) {
    int n = n0 + i;
    os[i][t] = (n < N) ? o[(size_t)n * 128 + t] : 0.f;
  }
  __syncthreads();
  if (t < 48) {
    int nn = t / 3, j = t % 3;
    int n = n0 + nn;
    if (n < N) {
      float s = b2s[j];
#pragma unroll 16
      for (int k = 0; k < 128; ++k) s += os[nn][k] * w2s[k * 3 + j];
      out[(size_t)n * 3 + j] = fmaxf(s, 0.f);
    }
  }
}

// ---------------------------------------------------------------------------
extern "C" void kernel_launch(void* const* d_in, const int* in_sizes, int n_in,
                              void* d_out, int out_size, void* d_ws, size_t ws_size,
                              hipStream_t stream) {
  const float* x       = (const float*)d_in[0];
  const int*   ei      = (const int*)  d_in[1];
  const float* ea      = (const float*)d_in[2];
  const float* lin_w   = (const float*)d_in[3];
  const float* lin_b   = (const float*)d_in[4];
  const float* msg_w1  = (const float*)d_in[5];
  const float* msg_b1  = (const float*)d_in[6];
  const float* msg_w2  = (const float*)d_in[7];
  const float* msg_b2  = (const float*)d_in[8];
  const float* upd_w1  = (const float*)d_in[9];
  const float* upd_b1  = (const float*)d_in[10];
  const float* upd_w2  = (const float*)d_in[11];
  const float* upd_b2  = (const float*)d_in[12];
  const float* head_w1 = (const float*)d_in[13];
  const float* head_b1 = (const float*)d_in[14];
  const float* head_w2 = (const float*)d_in[15];
  const float* head_b2 = (const float*)d_in[16];

  int N = in_sizes[0] / 16;
  int E = in_sizes[1] / 2;
  const int* src = ei;
  const int* dst = ei + E;

  float* ws  = (float*)d_ws;
  size_t NH  = (size_t)N * 128;
  float* h   = ws;
  float* hw  = ws + NH;        // also reused as head 'o'
  float* agg = ws + 2 * NH;
  float* u1  = ws + 3 * NH;
  float* cnt = ws + 4 * NH;
  float* out = (float*)d_out;

  int ngrid = (N + TILE_M - 1) / TILE_M;
  int egrid = (E + TILE_M - 1) / TILE_M;

  hipMemsetAsync(cnt, 0, (size_t)N * sizeof(float), stream);
  lin_in_kernel<<<(N + 15) / 16, 128, 0, stream>>>(x, lin_w, lin_b, h, N);
  count_kernel<<<(E + 255) / 256, 256, 0, stream>>>(dst, cnt, E);

  for (int l = 0; l < 4; ++l) {
    const float* mw1 = msg_w1 + (size_t)l * 132 * 128;   // rows 0..127: h part
    const float* wea = mw1 + 128 * 128;                  // rows 128..131: ea part
    // hw = h @ mw1[:128] + b1   (bias folded here; no relu)
    node_gemm<<<ngrid, 128, 0, stream>>>(h, mw1, 128, nullptr, nullptr, 0,
                                         nullptr, msg_b1 + l * 128, nullptr,
                                         hw, N, 0);
    hipMemsetAsync(agg, 0, NH * sizeof(float), stream);
    edge_kernel<<<egrid, 128, 0, stream>>>(hw, ea, src, dst,
                                           msg_w2 + (size_t)l * 128 * 128, wea,
                                           msg_b2 + l * 128, agg, E);
    // u1 = relu(h @ Wu1a + (agg/cnt) @ Wu1b + b)
    const float* wu1 = upd_w1 + (size_t)l * 256 * 128;
    node_gemm<<<ngrid, 128, 0, stream>>>(h, wu1, 128, agg, wu1 + 128 * 128, 128,
                                         cnt, upd_b1 + l * 128, nullptr,
                                         u1, N, 1);
    // h = relu(u1 @ Wu2 + b + h)
    node_gemm<<<ngrid, 128, 0, stream>>>(u1, upd_w2 + (size_t)l * 128 * 128, 128,
                                         nullptr, nullptr, 0, nullptr,
                                         upd_b2 + l * 128, h, h, N, 1);
  }
  // o = relu(h @ head_w1 + b1) -> reuse hw buffer
  node_gemm<<<ngrid, 128, 0, stream>>>(h, head_w1, 128, nullptr, nullptr, 0,
                                       nullptr, head_b1, nullptr, hw, N, 1);
  head_out_kernel<<<(N + 15) / 16, 128, 0, stream>>>(hw, head_w2, head_b2, out, N);
}

// Round 3
// 1703.266 us; speedup vs baseline: 8.8623x; 8.8623x over previous
//
#include <hip/hip_runtime.h>

// MeshGNN bf16-MFMA version. N=50000, E=600000, H=128, L=4.
// Identity: h[src]@W == (h@W)[src] -> msg layer 1 = node GEMM (hw, bf16 out)
//           + per-edge rank-4 edge_attr term (fp32 VALU).
// All 128-K GEMMs via mfma_f32_16x16x32_bf16, fp32 accum. Residual stream,
// aggregation atomics stay fp32; only GEMM inputs are bf16-rounded.
// R2 bugfix: Ws staging used uint4 as 16 ushorts (it is 8) -> half of the
// weight tile was uninitialized LDS -> inf. Now stages all 2048 chunks.

typedef __bf16 bf16x8 __attribute__((ext_vector_type(8)));
typedef float f32x4 __attribute__((ext_vector_type(4)));

__device__ inline ushort f2bf(float f) {
  unsigned u = __builtin_bit_cast(unsigned, f);
  unsigned r = (u + 0x7fff + ((u >> 16) & 1)) >> 16;
  return (ushort)r;
}
__device__ inline float bf2f(ushort h) {
  unsigned u = ((unsigned)h) << 16;
  return __builtin_bit_cast(float, u);
}

// ---------------------------------------------------------------------------
// lin_in: h = relu(x @ Win + b)   [N,16] @ [16,128], fp32 (cheap)
__global__ __launch_bounds__(128) void lin_in_kernel(
    const float* __restrict__ x, const float* __restrict__ W,
    const float* __restrict__ b, float* __restrict__ h, int N) {
  __shared__ float xs[16][16];
  int t = threadIdx.x;
  int n0 = blockIdx.x * 16;
  for (int i = t; i < 256; i += 128) {
    int r = i >> 4, c = i & 15;
    int n = n0 + r;
    xs[r][c] = (n < N) ? x[(size_t)n * 16 + c] : 0.f;
  }
  __syncthreads();
  float wcol[16];
#pragma unroll
  for (int k = 0; k < 16; ++k) wcol[k] = W[k * 128 + t];
  float bb = b[t];
  for (int i = 0; i < 16; ++i) {
    int n = n0 + i;
    if (n >= N) break;
    float s = bb;
#pragma unroll
    for (int k = 0; k < 16; ++k) s += xs[i][k] * wcol[k];
    h[(size_t)n * 128 + t] = fmaxf(s, 0.f);
  }
}

// ---------------------------------------------------------------------------
__global__ __launch_bounds__(256) void count_kernel(const int* __restrict__ dst,
                                                    float* __restrict__ cnt, int E) {
  int e = blockIdx.x * 256 + threadIdx.x;
  if (e < E) atomicAdd(&cnt[dst[e]], 1.0f);
}
__global__ __launch_bounds__(256) void inv_kernel(float* __restrict__ cnt, int N) {
  int i = blockIdx.x * 256 + threadIdx.x;
  if (i < N) cnt[i] = 1.f / fmaxf(cnt[i], 1.f);
}

// ---------------------------------------------------------------------------
// Weight convert+transpose: Wt[n][k] = bf16(W[k][n]), all K=128 matrices.
struct WPtrs { const float* src[21]; };
__global__ __launch_bounds__(256) void wconv_kernel(WPtrs p, ushort* __restrict__ wtb) {
  int m = blockIdx.y;
  int idx = blockIdx.x * 256 + threadIdx.x;   // 0..16383
  int n = idx >> 7, k = idx & 127;
  wtb[(size_t)m * 16384 + idx] = f2bf(p.src[m][k * 128 + n]);
}

// ---------------------------------------------------------------------------
// Node GEMM: C[M][128] = act( bf16(A1)@W1 + bf16(A2*inv)@W2 + bias + res )
// Wt* are bf16 [128 n][128 k]. 256 threads, 64-row tile, MFMA 16x16x32.
__global__ __launch_bounds__(256) void node_gemm_mfma(
    const float* __restrict__ A1, const ushort* __restrict__ Wt1,
    const float* __restrict__ A2, const ushort* __restrict__ Wt2,
    const float* __restrict__ inv, const float* __restrict__ bias,
    const float* __restrict__ res, float* __restrict__ Cf,
    ushort* __restrict__ Cb, int M, int relu_flag) {
  __shared__ ushort As[64 * 136];
  __shared__ ushort Ws[128 * 136];
  int t = threadIdx.x;
  int m0 = blockIdx.x * 64;
  int lane = t & 63, wave = t >> 6;

  f32x4 acc[8];
#pragma unroll
  for (int i = 0; i < 8; ++i)
#pragma unroll
    for (int j = 0; j < 4; ++j) acc[i][j] = 0.f;

  for (int op = 0; op < 2; ++op) {
    const float* A = op ? A2 : A1;
    const ushort* Wt = op ? Wt2 : Wt1;
    if (!A) break;
    // stage Wt -> Ws [128][136]; uint4 = 8 ushorts; 16 chunks per 128-el row
    for (int i = t; i < 128 * 16; i += 256) {
      int r = i >> 4, c = i & 15;
      *(uint4*)&Ws[r * 136 + c * 8] = *(const uint4*)&Wt[r * 128 + c * 8];
    }
    // stage A (fp32 -> bf16) -> As [64][136]; thread t: row t>>2, 32-el quarter
    {
      int row = t >> 2, q = t & 3;
      int m = m0 + row;
      union { ushort u16[32]; uint4 u4[4]; } tmp;
      if (m < M) {
        float s = (op && inv) ? inv[m] : 1.f;
        const float* Ap = A + (size_t)m * 128 + q * 32;
#pragma unroll
        for (int j = 0; j < 8; ++j) {
          float4 v = *(const float4*)&Ap[j * 4];
          tmp.u16[j * 4 + 0] = f2bf(v.x * s);
          tmp.u16[j * 4 + 1] = f2bf(v.y * s);
          tmp.u16[j * 4 + 2] = f2bf(v.z * s);
          tmp.u16[j * 4 + 3] = f2bf(v.w * s);
        }
      } else {
#pragma unroll
        for (int j = 0; j < 32; ++j) tmp.u16[j] = 0;
      }
#pragma unroll
      for (int j = 0; j < 4; ++j)
        *(uint4*)&As[row * 136 + q * 32 + j * 8] = tmp.u4[j];
    }
    __syncthreads();
    // compute: wave handles rows wave*16..+15
    int arow = (wave * 16 + (lane & 15)) * 136;
    int kq = (lane >> 4) * 8;
    int cl = lane & 15;
#pragma unroll
    for (int ks = 0; ks < 4; ++ks) {
      bf16x8 af = *(const bf16x8*)&As[arow + ks * 32 + kq];
#pragma unroll
      for (int ct = 0; ct < 8; ++ct) {
        bf16x8 bf = *(const bf16x8*)&Ws[(ct * 16 + cl) * 136 + ks * 32 + kq];
        acc[ct] = __builtin_amdgcn_mfma_f32_16x16x32_bf16(af, bf, acc[ct], 0, 0, 0);
      }
    }
    __syncthreads();
  }
  // epilogue: D row = (lane>>4)*4+reg, col = ct*16 + (lane&15)
  int cl = lane & 15;
#pragma unroll
  for (int reg = 0; reg < 4; ++reg) {
    int m = m0 + wave * 16 + (lane >> 4) * 4 + reg;
    if (m >= M) continue;
    size_t rowoff = (size_t)m * 128;
#pragma unroll
    for (int ct = 0; ct < 8; ++ct) {
      int col = ct * 16 + cl;
      float v = acc[ct][reg] + (bias ? bias[col] : 0.f);
      if (res) v += res[rowoff + col];
      if (relu_flag) v = fmaxf(v, 0.f);
      if (Cf) Cf[rowoff + col] = v;
      else Cb[rowoff + col] = f2bf(v);
    }
  }
}

// ---------------------------------------------------------------------------
// Edge kernel, 128 edges/block:
//   m1 = relu(hw[src] + ea @ Wea)  (bf16 gather, fp32 rank-4, bf16 to LDS)
//   m2 = relu(m1 @ W2t + b2)       (MFMA)
//   atomicAdd(agg[dst], m2)        (skip zeros)
__global__ __launch_bounds__(256) void edge_kernel_mfma(
    const ushort* __restrict__ hw, const float* __restrict__ ea,
    const int* __restrict__ src, const int* __restrict__ dst,
    const ushort* __restrict__ W2t, const float* __restrict__ Wea,
    const float* __restrict__ b2, float* __restrict__ agg, int E) {
  __shared__ ushort m1s[128 * 136];
  __shared__ ushort Ws[128 * 136];
  __shared__ float WeaS[4][128];
  __shared__ float b2s[128];
  int t = threadIdx.x;
  int e0 = blockIdx.x * 128;
  int lane = t & 63, wave = t >> 6;

  for (int i = t; i < 512; i += 256) WeaS[i >> 7][i & 127] = Wea[i];
  if (t < 128) b2s[t] = b2[t];
  // stage W2t -> Ws; uint4 = 8 ushorts; 16 chunks per row
  for (int i = t; i < 128 * 16; i += 256) {
    int r = i >> 4, c = i & 15;
    *(uint4*)&Ws[r * 136 + c * 8] = *(const uint4*)&W2t[r * 128 + c * 8];
  }
  __syncthreads();

  // phase 1: thread t -> edge t>>1, 64-feature half (t&1)
  {
    int el = t >> 1, half = (t & 1) * 64;
    int eg = e0 + el;
    union { ushort u16[64]; uint4 u4[8]; } buf;
    if (eg < E) {
      int s = src[eg];
      float4 eav = *(const float4*)&ea[(size_t)eg * 4];
      const ushort* hr = hw + (size_t)s * 128 + half;
#pragma unroll
      for (int j0 = 0; j0 < 64; j0 += 8) {
        uint4 hv = *(const uint4*)&hr[j0];
        const ushort* hs = (const ushort*)&hv;
#pragma unroll
        for (int j = 0; j < 8; ++j) {
          int col = half + j0 + j;
          float f = bf2f(hs[j]) + eav.x * WeaS[0][col] + eav.y * WeaS[1][col] +
                    eav.z * WeaS[2][col] + eav.w * WeaS[3][col];
          buf.u16[j0 + j] = f2bf(fmaxf(f, 0.f));
        }
      }
    } else {
#pragma unroll
      for (int j = 0; j < 64; ++j) buf.u16[j] = 0;
    }
#pragma unroll
    for (int j0 = 0; j0 < 8; ++j0)
      *(uint4*)&m1s[el * 136 + half + j0 * 8] = buf.u4[j0];
  }
  __syncthreads();

  // phase 2: wave handles 32 edge-rows (2 row-blocks of 16)
  f32x4 acc[2][8];
#pragma unroll
  for (int r = 0; r < 2; ++r)
#pragma unroll
    for (int i = 0; i < 8; ++i)
#pragma unroll
      for (int j = 0; j < 4; ++j) acc[r][i][j] = 0.f;

  int kq = (lane >> 4) * 8;
  int cl = lane & 15;
  int a0 = (wave * 32 + cl) * 136;
  int a1 = (wave * 32 + 16 + cl) * 136;
#pragma unroll
  for (int ks = 0; ks < 4; ++ks) {
    bf16x8 af0 = *(const bf16x8*)&m1s[a0 + ks * 32 + kq];
    bf16x8 af1 = *(const bf16x8*)&m1s[a1 + ks * 32 + kq];
#pragma unroll
    for (int ct = 0; ct < 8; ++ct) {
      bf16x8 bf = *(const bf16x8*)&Ws[(ct * 16 + cl) * 136 + ks * 32 + kq];
      acc[0][ct] = __builtin_amdgcn_mfma_f32_16x16x32_bf16(af0, bf, acc[0][ct], 0, 0, 0);
      acc[1][ct] = __builtin_amdgcn_mfma_f32_16x16x32_bf16(af1, bf, acc[1][ct], 0, 0, 0);
    }
  }

  // epilogue: bias + relu + atomic scatter (skip zeros)
#pragma unroll
  for (int rb = 0; rb < 2; ++rb) {
#pragma unroll
    for (int reg = 0; reg < 4; ++reg) {
      int er = wave * 32 + rb * 16 + (lane >> 4) * 4 + reg;
      int ege = e0 + er;
      if (ege >= E) continue;
      int d = dst[ege];
      float* base = &agg[(size_t)d * 128 + cl];
#pragma unroll
      for (int ct = 0; ct < 8; ++ct) {
        float v = fmaxf(acc[rb][ct][reg] + b2s[ct * 16 + cl], 0.f);
        if (v > 0.f) atomicAdd(&base[ct * 16], v);
      }
    }
  }
}

// ---------------------------------------------------------------------------
// head stage 2: out = relu(o @ head_w2 + head_b2)   [N,128] @ [128,3], fp32
__global__ __launch_bounds__(128) void head_out_kernel(
    const float* __restrict__ o, const float* __restrict__ w2,
    const float* __restrict__ b2, float* __restrict__ out, int N) {
  __shared__ float os[16][128];
  __shared__ float w2s[384];
  __shared__ float b2s[3];
  int t = threadIdx.x;
  for (int i = t; i < 384; i += 128) w2s[i] = w2[i];
  if (t < 3) b2s[t] = b2[t];
  int n0 = blockIdx.x * 16;
  for (int i = 0; i < 16; ++i) {
    int n = n0 + i;
    os[i][t] = (n < N) ? o[(size_t)n * 128 + t] : 0.f;
  }
  __syncthreads();
  if (t < 48) {
    int nn = t / 3, j = t % 3;
    int n = n0 + nn;
    if (n < N) {
      float s = b2s[j];
#pragma unroll 16
      for (int k = 0; k < 128; ++k) s += os[nn][k] * w2s[k * 3 + j];
      out[(size_t)n * 3 + j] = fmaxf(s, 0.f);
    }
  }
}

// ---------------------------------------------------------------------------
extern "C" void kernel_launch(void* const* d_in, const int* in_sizes, int n_in,
                              void* d_out, int out_size, void* d_ws, size_t ws_size,
                              hipStream_t stream) {
  const float* x       = (const float*)d_in[0];
  const int*   ei      = (const int*)  d_in[1];
  const float* ea      = (const float*)d_in[2];
  const float* lin_w   = (const float*)d_in[3];
  const float* lin_b   = (const float*)d_in[4];
  const float* msg_w1  = (const float*)d_in[5];
  const float* msg_b1  = (const float*)d_in[6];
  const float* msg_w2  = (const float*)d_in[7];
  const float* msg_b2  = (const float*)d_in[8];
  const float* upd_w1  = (const float*)d_in[9];
  const float* upd_b1  = (const float*)d_in[10];
  const float* upd_w2  = (const float*)d_in[11];
  const float* upd_b2  = (const float*)d_in[12];
  const float* head_w1 = (const float*)d_in[13];
  const float* head_b1 = (const float*)d_in[14];
  const float* head_w2 = (const float*)d_in[15];
  const float* head_b2 = (const float*)d_in[16];

  int N = in_sizes[0] / 16;
  int E = in_sizes[1] / 2;
  const int* src = ei;
  const int* dst = ei + E;

  float* ws = (float*)d_ws;
  size_t NH = (size_t)N * 128;
  size_t Nr = ((size_t)N + 3) & ~(size_t)3;
  float*  h    = ws;                      // [N][128] fp32
  float*  u1   = ws + NH;                 // [N][128] fp32 (also head 'o')
  float*  agg  = ws + 2 * NH;             // [N][128] fp32
  float*  cnt  = ws + 3 * NH;             // [N] fp32 -> becomes inv
  ushort* hwb  = (ushort*)(ws + 3 * NH + Nr);          // [N][128] bf16
  ushort* wtb  = (ushort*)(ws + 3 * NH + Nr + NH / 2); // 21 x [128][128] bf16
  float*  out  = (float*)d_out;

  // weight conversion table: per layer {mw1t, mw2t, wu1at, wu1bt, wu2t}, then head1t
  WPtrs wp;
  for (int l = 0; l < 4; ++l) {
    wp.src[l * 5 + 0] = msg_w1 + (size_t)l * 132 * 128;
    wp.src[l * 5 + 1] = msg_w2 + (size_t)l * 128 * 128;
    wp.src[l * 5 + 2] = upd_w1 + (size_t)l * 256 * 128;
    wp.src[l * 5 + 3] = upd_w1 + (size_t)l * 256 * 128 + 128 * 128;
    wp.src[l * 5 + 4] = upd_w2 + (size_t)l * 128 * 128;
  }
  wp.src[20] = head_w1;

  int ngrid = (N + 63) / 64;
  int egrid = (E + 127) / 128;

  hipMemsetAsync(cnt, 0, (size_t)N * sizeof(float), stream);
  wconv_kernel<<<dim3(64, 21), 256, 0, stream>>>(wp, wtb);
  lin_in_kernel<<<(N + 15) / 16, 128, 0, stream>>>(x, lin_w, lin_b, h, N);
  count_kernel<<<(E + 255) / 256, 256, 0, stream>>>(dst, cnt, E);
  inv_kernel<<<(N + 255) / 256, 256, 0, stream>>>(cnt, N);

  for (int l = 0; l < 4; ++l) {
    const ushort* mw1t  = wtb + (size_t)(l * 5 + 0) * 16384;
    const ushort* mw2t  = wtb + (size_t)(l * 5 + 1) * 16384;
    const ushort* wu1at = wtb + (size_t)(l * 5 + 2) * 16384;
    const ushort* wu1bt = wtb + (size_t)(l * 5 + 3) * 16384;
    const ushort* wu2t  = wtb + (size_t)(l * 5 + 4) * 16384;
    const float*  wea   = msg_w1 + (size_t)l * 132 * 128 + 128 * 128;

    // hw(bf16) = h @ mw1 + msg_b1   (no relu)
    node_gemm_mfma<<<ngrid, 256, 0, stream>>>(h, mw1t, nullptr, nullptr, nullptr,
                                              msg_b1 + l * 128, nullptr,
                                              nullptr, hwb, N, 0);
    hipMemsetAsync(agg, 0, NH * sizeof(float), stream);
    edge_kernel_mfma<<<egrid, 256, 0, stream>>>(hwb, ea, src, dst, mw2t, wea,
                                                msg_b2 + l * 128, agg, E);
    // u1 = relu(h@Wu1a + (agg*inv)@Wu1b + b)
    node_gemm_mfma<<<ngrid, 256, 0, stream>>>(h, wu1at, agg, wu1bt, cnt,
                                              upd_b1 + l * 128, nullptr,
                                              u1, nullptr, N, 1);
    // h = relu(u1@Wu2 + b + h)
    node_gemm_mfma<<<ngrid, 256, 0, stream>>>(u1, wu2t, nullptr, nullptr, nullptr,
                                              upd_b2 + l * 128, h,
                                              h, nullptr, N, 1);
  }
  // o = relu(h @ head_w1 + b1) -> u1 buffer (fp32)
  node_gemm_mfma<<<ngrid, 256, 0, stream>>>(h, wtb + (size_t)20 * 16384, nullptr,
                                            nullptr, nullptr, head_b1, nullptr,
                                            u1, nullptr, N, 1);
  head_out_kernel<<<(N + 15) / 16, 128, 0, stream>>>(u1, head_w2, head_b2, out, N);
}

// Round 4
// 1025.393 us; speedup vs baseline: 14.7211x; 1.6611x over previous
//
#include <hip/hip_runtime.h>

// MeshGNN bf16-MFMA v3. N=50000, E=600000, H=128, L=4.
// R3 changes vs R2:
//  (1) dst-sorted edge processing (counting sort per call) + per-tile
//      segmented reduction: complete dst-groups -> plain store, boundary
//      groups -> atomicAdd. Cuts ~38M atomics/dispatch to ~1.5M.
//  (2) fused node phase: u1 -> u2(+res) -> next-layer hw (or head) chained
//      through LDS in one kernel per layer; lin_in fused with hw0.

typedef __bf16 bf16x8 __attribute__((ext_vector_type(8)));
typedef float f32x4 __attribute__((ext_vector_type(4)));

__device__ inline ushort f2bf(float f) {
  unsigned u = __builtin_bit_cast(unsigned, f);
  unsigned r = (u + 0x7fff + ((u >> 16) & 1)) >> 16;
  return (ushort)r;
}
__device__ inline float bf2f(ushort h) {
  unsigned u = ((unsigned)h) << 16;
  return __builtin_bit_cast(float, u);
}

// stage bf16 weight [128n][128k] -> LDS [128][136]
__device__ inline void stage_w(ushort* Ws, const ushort* __restrict__ Wt, int t) {
#pragma unroll
  for (int i = t; i < 2048; i += 256) {
    int r = i >> 4, c = i & 15;
    *(uint4*)&Ws[r * 136 + c * 8] = *(const uint4*)&Wt[r * 128 + c * 8];
  }
}
// acc += A(64x128 in LDS, rows wave*16..+15) x W(128x128 in LDS)
__device__ inline void mfma_4ks(f32x4* acc, const ushort* A, const ushort* Ws,
                                int wave, int lane) {
  int cl = lane & 15, kq = (lane >> 4) * 8;
  int arow = (wave * 16 + cl) * 136;
#pragma unroll
  for (int ks = 0; ks < 4; ++ks) {
    bf16x8 af = *(const bf16x8*)&A[arow + ks * 32 + kq];
#pragma unroll
    for (int ct = 0; ct < 8; ++ct) {
      bf16x8 bf = *(const bf16x8*)&Ws[(ct * 16 + cl) * 136 + ks * 32 + kq];
      acc[ct] = __builtin_amdgcn_mfma_f32_16x16x32_bf16(af, bf, acc[ct], 0, 0, 0);
    }
  }
}

// ---------------------------------------------------------------------------
// preprocessing: counting sort of edges by dst
__global__ __launch_bounds__(256) void count_int_kernel(const int* __restrict__ dst,
                                                        int* __restrict__ cnti, int E) {
  int e = blockIdx.x * 256 + threadIdx.x;
  if (e < E) atomicAdd(&cnti[dst[e]], 1);
}
__global__ __launch_bounds__(256) void inv_kernel(const int* __restrict__ cnti,
                                                  float* __restrict__ invf, int N) {
  int i = blockIdx.x * 256 + threadIdx.x;
  if (i < N) invf[i] = 1.f / (float)max(cnti[i], 1);
}
__global__ __launch_bounds__(1024) void prefix_kernel(const int* __restrict__ cnti,
                                                      int* __restrict__ rowptr, int N) {
  __shared__ int part[1024];
  int t = threadIdx.x;
  int per = (N + 1023) / 1024;
  int base = t * per;
  int s = 0;
  for (int i = 0; i < per; ++i) {
    int idx = base + i;
    if (idx < N) s += cnti[idx];
  }
  part[t] = s;
  __syncthreads();
  for (int off = 1; off < 1024; off <<= 1) {
    int v = (t >= off) ? part[t - off] : 0;
    __syncthreads();
    part[t] += v;
    __syncthreads();
  }
  int run = (t == 0) ? 0 : part[t - 1];
  for (int i = 0; i < per; ++i) {
    int idx = base + i;
    if (idx < N) { rowptr[idx] = run; run += cnti[idx]; }
  }
  if (t == 1023) rowptr[N] = part[1023];
}
__global__ __launch_bounds__(256) void scatter_kernel(
    const int* __restrict__ src, const int* __restrict__ dst,
    const float4* __restrict__ ea, const int* __restrict__ rowptr,
    int* __restrict__ tmpc, int* __restrict__ srcs, int* __restrict__ dsts,
    float4* __restrict__ eas, int E) {
  int e = blockIdx.x * 256 + threadIdx.x;
  if (e >= E) return;
  int d = dst[e];
  int r = atomicAdd(&tmpc[d], 1);
  int p = rowptr[d] + r;
  srcs[p] = src[e];
  dsts[p] = d;
  eas[p] = ea[e];
}

// ---------------------------------------------------------------------------
// Weight convert+transpose: Wt[n][k] = bf16(W[k][n]). m==21: lin [128][32] K-pad.
struct WPtrs { const float* src[22]; };
__global__ __launch_bounds__(256) void wconv_kernel(WPtrs p, ushort* __restrict__ wtb,
                                                    ushort* __restrict__ wlin) {
  int m = blockIdx.y;
  int idx = blockIdx.x * 256 + threadIdx.x;
  if (m == 21) {
    if (idx >= 4096) return;
    int n = idx >> 5, k = idx & 31;
    wlin[idx] = (k < 16) ? f2bf(p.src[21][k * 128 + n]) : (ushort)0;
  } else {
    int n = idx >> 7, k = idx & 127;
    wtb[(size_t)m * 16384 + idx] = f2bf(p.src[m][k * 128 + n]);
  }
}

// ---------------------------------------------------------------------------
// lin_hw: h = relu(x@Win+b) ; hwb = bf16(h@Mw1_0 + mb1_0)
__global__ __launch_bounds__(256) void lin_hw_kernel(
    const float* __restrict__ x, const ushort* __restrict__ wlin,
    const float* __restrict__ lb, const ushort* __restrict__ mw1t,
    const float* __restrict__ mb1, float* __restrict__ h,
    ushort* __restrict__ hwb, int N) {
  __shared__ char smem[69632] __attribute__((aligned(16)));
  ushort* xb  = (ushort*)smem;            // [64*32]
  ushort* wsl = (ushort*)(smem + 4096);   // [128*32]
  ushort* As1 = (ushort*)(smem + 12288);  // [64*136]
  ushort* Ws  = (ushort*)(smem + 34816);  // [128*136]
  int t = threadIdx.x, lane = t & 63, wave = t >> 6;
  int m0 = blockIdx.x * 64;
  int cl = lane & 15, kq = (lane >> 4) * 8;

  for (int i = t; i < 2048; i += 256) {
    int row = i >> 5, c = i & 31;
    int m = m0 + row;
    xb[i] = (c < 16 && m < N) ? f2bf(x[(size_t)m * 16 + c]) : (ushort)0;
  }
  for (int i = t; i < 4096 / 8; i += 256)
    *(uint4*)&wsl[i * 8] = *(const uint4*)&wlin[i * 8];
  stage_w(Ws, mw1t, t);
  __syncthreads();

  f32x4 acc[8];
#pragma unroll
  for (int i = 0; i < 8; ++i)
#pragma unroll
    for (int j = 0; j < 4; ++j) acc[i][j] = 0.f;
  {
    bf16x8 af = *(const bf16x8*)&xb[(wave * 16 + cl) * 32 + kq];
#pragma unroll
    for (int ct = 0; ct < 8; ++ct) {
      bf16x8 bf = *(const bf16x8*)&wsl[(ct * 16 + cl) * 32 + kq];
      acc[ct] = __builtin_amdgcn_mfma_f32_16x16x32_bf16(af, bf, acc[ct], 0, 0, 0);
    }
  }
  // h0 = relu(acc + lb) -> global fp32 + As1 bf16
#pragma unroll
  for (int reg = 0; reg < 4; ++reg) {
    int row = wave * 16 + (lane >> 4) * 4 + reg;
    int m = m0 + row;
#pragma unroll
    for (int ct = 0; ct < 8; ++ct) {
      int col = ct * 16 + cl;
      float v = fmaxf(acc[ct][reg] + lb[col], 0.f);
      if (m < N) h[(size_t)m * 128 + col] = v;
      As1[row * 136 + col] = f2bf(v);
    }
  }
  __syncthreads();
  f32x4 acc2[8];
#pragma unroll
  for (int i = 0; i < 8; ++i)
#pragma unroll
    for (int j = 0; j < 4; ++j) acc2[i][j] = 0.f;
  mfma_4ks(acc2, As1, Ws, wave, lane);
#pragma unroll
  for (int reg = 0; reg < 4; ++reg) {
    int m = m0 + wave * 16 + (lane >> 4) * 4 + reg;
    if (m >= N) continue;
#pragma unroll
    for (int ct = 0; ct < 8; ++ct) {
      int col = ct * 16 + cl;
      hwb[(size_t)m * 128 + col] = f2bf(acc2[ct][reg] + mb1[col]);
    }
  }
}

// ---------------------------------------------------------------------------
// edge kernel v3: 128 sorted edges/tile.
//   m1 = relu(hw[srcs[p]] + eas[p] @ Wea); m2 = relu(m1@W2 + b2) -> LDS fp32
//   segmented reduce over dst groups: complete -> store, boundary -> atomic
__global__ __launch_bounds__(256) void edge_kernel_v3(
    const ushort* __restrict__ hw, const float4* __restrict__ eas,
    const int* __restrict__ srcs, const int* __restrict__ dsts,
    const ushort* __restrict__ W2t, const float* __restrict__ Wea,
    const float* __restrict__ b2, float* __restrict__ agg, int E) {
  __shared__ char smem[69632] __attribute__((aligned(16)));
  ushort* m1s = (ushort*)smem;            // [128*136]
  ushort* Ws  = (ushort*)(smem + 34816);  // [128*136]
  float*  m2f = (float*)smem;             // [128*132] overlays (post-MFMA)
  __shared__ float WeaS[4][128];
  __shared__ float b2s[128];
  __shared__ int dss[128];
  __shared__ int dbound[2];
  int t = threadIdx.x, lane = t & 63, wave = t >> 6;
  int p0 = blockIdx.x * 128;
  int rows = min(128, E - p0);

  for (int i = t; i < 512; i += 256) WeaS[i >> 7][i & 127] = Wea[i];
  if (t < 128) {
    b2s[t] = b2[t];
    dss[t] = (p0 + t < E) ? dsts[p0 + t] : -1;
  }
  if (t == 0) dbound[0] = (p0 > 0) ? dsts[p0 - 1] : -2;
  if (t == 1) dbound[1] = (p0 + rows < E) ? dsts[p0 + rows] : -3;
  stage_w(Ws, W2t, t);

  // phase 1: thread t -> edge t>>1, 64-feature half (t&1)
  {
    int el = t >> 1, half = (t & 1) * 64;
    int pe = p0 + el;
    union { ushort u16[64]; uint4 u4[8]; } buf;
    if (pe < E) {
      int s = srcs[pe];
      float4 eav = eas[pe];
      const ushort* hr = hw + (size_t)s * 128 + half;
      __syncthreads();  // WeaS ready (also Ws/dss)
#pragma unroll
      for (int j0 = 0; j0 < 64; j0 += 8) {
        uint4 hv = *(const uint4*)&hr[j0];
        const ushort* hs = (const ushort*)&hv;
#pragma unroll
        for (int j = 0; j < 8; ++j) {
          int col = half + j0 + j;
          float f = bf2f(hs[j]) + eav.x * WeaS[0][col] + eav.y * WeaS[1][col] +
                    eav.z * WeaS[2][col] + eav.w * WeaS[3][col];
          buf.u16[j0 + j] = f2bf(fmaxf(f, 0.f));
        }
      }
    } else {
      __syncthreads();
#pragma unroll
      for (int j = 0; j < 64; ++j) buf.u16[j] = 0;
    }
#pragma unroll
    for (int j0 = 0; j0 < 8; ++j0)
      *(uint4*)&m1s[el * 136 + half + j0 * 8] = buf.u4[j0];
  }
  __syncthreads();

  // phase 2: MFMA, wave handles 32 edge-rows
  f32x4 acc[2][8];
#pragma unroll
  for (int r = 0; r < 2; ++r)
#pragma unroll
    for (int i = 0; i < 8; ++i)
#pragma unroll
      for (int j = 0; j < 4; ++j) acc[r][i][j] = 0.f;
  int kq = (lane >> 4) * 8;
  int cl = lane & 15;
  int a0 = (wave * 32 + cl) * 136;
  int a1 = (wave * 32 + 16 + cl) * 136;
#pragma unroll
  for (int ks = 0; ks < 4; ++ks) {
    bf16x8 af0 = *(const bf16x8*)&m1s[a0 + ks * 32 + kq];
    bf16x8 af1 = *(const bf16x8*)&m1s[a1 + ks * 32 + kq];
#pragma unroll
    for (int ct = 0; ct < 8; ++ct) {
      bf16x8 bf = *(const bf16x8*)&Ws[(ct * 16 + cl) * 136 + ks * 32 + kq];
      acc[0][ct] = __builtin_amdgcn_mfma_f32_16x16x32_bf16(af0, bf, acc[0][ct], 0, 0, 0);
      acc[1][ct] = __builtin_amdgcn_mfma_f32_16x16x32_bf16(af1, bf, acc[1][ct], 0, 0, 0);
    }
  }
  __syncthreads();   // all MFMA LDS reads done before m2f overlay

  // m2 = relu(acc + b2) -> m2f fp32
#pragma unroll
  for (int rb = 0; rb < 2; ++rb)
#pragma unroll
    for (int reg = 0; reg < 4; ++reg) {
      int row = wave * 32 + rb * 16 + (lane >> 4) * 4 + reg;
#pragma unroll
      for (int ct = 0; ct < 8; ++ct) {
        int col = ct * 16 + cl;
        m2f[row * 132 + col] = fmaxf(acc[rb][ct][reg] + b2s[col], 0.f);
      }
    }
  __syncthreads();

  // phase 3: per-column segmented reduction; 2-way row split
  {
    int col = t & 127;
    int half = t >> 7;
    int r0 = half * 64;
    int r1 = min(rows, r0 + 64);
    if (r0 < r1) {
      int prevD = (half == 0) ? dbound[0] : dss[63];
      int afterD = (half == 0) ? ((rows > 64) ? dss[64] : dbound[1]) : dbound[1];
      float s = 0.f;
      int curd = dss[r0];
      bool first = true;
      for (int r = r0; r < r1; ++r) {
        int d = dss[r];
        if (d != curd) {
          if (curd >= 0) {
            bool open = (first && curd == prevD);
            float* addr = &agg[(size_t)curd * 128 + col];
            if (open) atomicAdd(addr, s); else *addr = s;
          }
          s = 0.f; curd = d; first = false;
        }
        s += m2f[r * 132 + col];
      }
      if (curd >= 0) {
        bool open = (first && curd == prevD) || (curd == afterD);
        float* addr = &agg[(size_t)curd * 128 + col];
        if (open) atomicAdd(addr, s); else *addr = s;
      }
    }
  }
}

// ---------------------------------------------------------------------------
// fused node phase per layer:
//   u1 = relu(h@Wu1a + (agg*inv)@Wu1b + b1)
//   u  = relu(u1@Wu2 + b2 + h)           -> h (in-place, skipped on last)
//   l<3 : hwb = bf16(u@Wn + bn)
//   l==3: o = relu(u@Wn + bn); out = relu(o@head_w2 + head_b2)
__global__ __launch_bounds__(256) void fused_update(
    const float* __restrict__ h, const float* __restrict__ agg,
    const float* __restrict__ inv, const ushort* __restrict__ Wu1a,
    const ushort* __restrict__ Wu1b, const ushort* __restrict__ Wu2,
    const float* __restrict__ b1, const float* __restrict__ b2,
    const ushort* __restrict__ Wn, const float* __restrict__ bn,
    float* __restrict__ h_out, ushort* __restrict__ hwb,
    const float* __restrict__ hw2, const float* __restrict__ hb2,
    float* __restrict__ out, int N, int is_last) {
  __shared__ char smem[69632] __attribute__((aligned(16)));
  ushort* As1 = (ushort*)smem;             // [64*136]
  ushort* As2 = (ushort*)(smem + 17408);   // [64*136]
  ushort* Ws  = (ushort*)(smem + 34816);   // [128*136]
  float* otile = (float*)smem;             // last: [64*130]
  float* w2s   = (float*)(smem + 33280);   // last: [384]
  int t = threadIdx.x, lane = t & 63, wave = t >> 6;
  int m0 = blockIdx.x * 64;
  int cl = lane & 15;

  // stage As1=bf16(h), As2=bf16(agg*inv)
  {
    int row = t >> 2, q = t & 3;
    int m = m0 + row;
    union { ushort u16[32]; uint4 u4[4]; } a, g;
    if (m < N) {
      const float* hp = h + (size_t)m * 128 + q * 32;
      const float* gp = agg + (size_t)m * 128 + q * 32;
      float s = inv[m];
#pragma unroll
      for (int j = 0; j < 8; ++j) {
        float4 hv = *(const float4*)&hp[j * 4];
        float4 gv = *(const float4*)&gp[j * 4];
        a.u16[j * 4 + 0] = f2bf(hv.x); a.u16[j * 4 + 1] = f2bf(hv.y);
        a.u16[j * 4 + 2] = f2bf(hv.z); a.u16[j * 4 + 3] = f2bf(hv.w);
        g.u16[j * 4 + 0] = f2bf(gv.x * s); g.u16[j * 4 + 1] = f2bf(gv.y * s);
        g.u16[j * 4 + 2] = f2bf(gv.z * s); g.u16[j * 4 + 3] = f2bf(gv.w * s);
      }
    } else {
#pragma unroll
      for (int j = 0; j < 32; ++j) { a.u16[j] = 0; g.u16[j] = 0; }
    }
#pragma unroll
    for (int j = 0; j < 4; ++j) {
      *(uint4*)&As1[row * 136 + q * 32 + j * 8] = a.u4[j];
      *(uint4*)&As2[row * 136 + q * 32 + j * 8] = g.u4[j];
    }
  }
  stage_w(Ws, Wu1a, t);
  __syncthreads();

  f32x4 acc[8];
#pragma unroll
  for (int i = 0; i < 8; ++i)
#pragma unroll
    for (int j = 0; j < 4; ++j) acc[i][j] = 0.f;
  mfma_4ks(acc, As1, Ws, wave, lane);
  __syncthreads();
  stage_w(Ws, Wu1b, t);
  __syncthreads();
  mfma_4ks(acc, As2, Ws, wave, lane);
  __syncthreads();

  // u1 -> As1 bf16 (own rows); restage Ws <- Wu2
#pragma unroll
  for (int reg = 0; reg < 4; ++reg) {
    int row = wave * 16 + (lane >> 4) * 4 + reg;
#pragma unroll
    for (int ct = 0; ct < 8; ++ct) {
      int col = ct * 16 + cl;
      As1[row * 136 + col] = f2bf(fmaxf(acc[ct][reg] + b1[col], 0.f));
    }
  }
  stage_w(Ws, Wu2, t);
  __syncthreads();

  f32x4 acc2[8];
#pragma unroll
  for (int i = 0; i < 8; ++i)
#pragma unroll
    for (int j = 0; j < 4; ++j) acc2[i][j] = 0.f;
  mfma_4ks(acc2, As1, Ws, wave, lane);
  __syncthreads();

  // u = relu(acc2 + b2 + h) -> h_out (not on last) + As1 bf16; Ws <- Wn
#pragma unroll
  for (int reg = 0; reg < 4; ++reg) {
    int row = wave * 16 + (lane >> 4) * 4 + reg;
    int m = m0 + row;
#pragma unroll
    for (int ct = 0; ct < 8; ++ct) {
      int col = ct * 16 + cl;
      float v = acc2[ct][reg] + b2[col];
      if (m < N) v += h[(size_t)m * 128 + col];
      v = fmaxf(v, 0.f);
      if (!is_last && m < N) h_out[(size_t)m * 128 + col] = v;
      As1[row * 136 + col] = f2bf(v);
    }
  }
  stage_w(Ws, Wn, t);
  __syncthreads();

  f32x4 acc3[8];
#pragma unroll
  for (int i = 0; i < 8; ++i)
#pragma unroll
    for (int j = 0; j < 4; ++j) acc3[i][j] = 0.f;
  mfma_4ks(acc3, As1, Ws, wave, lane);

  if (!is_last) {
#pragma unroll
    for (int reg = 0; reg < 4; ++reg) {
      int m = m0 + wave * 16 + (lane >> 4) * 4 + reg;
      if (m >= N) continue;
#pragma unroll
      for (int ct = 0; ct < 8; ++ct) {
        int col = ct * 16 + cl;
        hwb[(size_t)m * 128 + col] = f2bf(acc3[ct][reg] + bn[col]);
      }
    }
  } else {
    __syncthreads();  // As1/As2 reads done before otile overlay
#pragma unroll
    for (int reg = 0; reg < 4; ++reg) {
      int row = wave * 16 + (lane >> 4) * 4 + reg;
#pragma unroll
      for (int ct = 0; ct < 8; ++ct) {
        int col = ct * 16 + cl;
        otile[row * 130 + col] = fmaxf(acc3[ct][reg] + bn[col], 0.f);
      }
    }
    for (int i = t; i < 384; i += 256) w2s[i] = hw2[i];
    __syncthreads();
    if (t < 192) {
      int row = t / 3, c = t % 3;
      int m = m0 + row;
      if (m < N) {
        float s = hb2[c];
#pragma unroll 16
        for (int k = 0; k < 128; ++k) s += otile[row * 130 + k] * w2s[k * 3 + c];
        out[(size_t)m * 3 + c] = fmaxf(s, 0.f);
      }
    }
  }
}

// ---------------------------------------------------------------------------
extern "C" void kernel_launch(void* const* d_in, const int* in_sizes, int n_in,
                              void* d_out, int out_size, void* d_ws, size_t ws_size,
                              hipStream_t stream) {
  const float* x       = (const float*)d_in[0];
  const int*   ei      = (const int*)  d_in[1];
  const float* ea      = (const float*)d_in[2];
  const float* lin_w   = (const float*)d_in[3];
  const float* lin_b   = (const float*)d_in[4];
  const float* msg_w1  = (const float*)d_in[5];
  const float* msg_b1  = (const float*)d_in[6];
  const float* msg_w2  = (const float*)d_in[7];
  const float* msg_b2  = (const float*)d_in[8];
  const float* upd_w1  = (const float*)d_in[9];
  const float* upd_b1  = (const float*)d_in[10];
  const float* upd_w2  = (const float*)d_in[11];
  const float* upd_b2  = (const float*)d_in[12];
  const float* head_w1 = (const float*)d_in[13];
  const float* head_b1 = (const float*)d_in[14];
  const float* head_w2 = (const float*)d_in[15];
  const float* head_b2 = (const float*)d_in[16];

  int N = in_sizes[0] / 16;
  int E = in_sizes[1] / 2;
  const int* src = ei;
  const int* dst = ei + E;

  float* ws = (float*)d_ws;
  size_t NH = (size_t)N * 128;
  size_t Nr = ((size_t)N + 4) & ~(size_t)3;
  size_t Er = ((size_t)E + 3) & ~(size_t)3;
  size_t off = 0;
  float*  h    = ws + off; off += NH;
  float*  agg  = ws + off; off += NH;
  float4* eas  = (float4*)(ws + off); off += 4 * Er;
  float*  invf = ws + off; off += Nr;
  ushort* wtb  = (ushort*)(ws + off); off += (size_t)21 * 16384 / 2;
  ushort* wlin = (ushort*)(ws + off); off += 4096 / 2;
  ushort* hwb  = (ushort*)(ws + off); off += NH / 2;
  int*    cnti = (int*)(ws + off); off += Nr;
  int*    tmpc = (int*)(ws + off); off += Nr;
  int*    rowp = (int*)(ws + off); off += Nr;
  int*    srcs = (int*)(ws + off); off += Er;
  int*    dsts = (int*)(ws + off); off += Er;
  float*  out  = (float*)d_out;

  WPtrs wp;
  for (int l = 0; l < 4; ++l) {
    wp.src[l * 5 + 0] = msg_w1 + (size_t)l * 132 * 128;
    wp.src[l * 5 + 1] = msg_w2 + (size_t)l * 128 * 128;
    wp.src[l * 5 + 2] = upd_w1 + (size_t)l * 256 * 128;
    wp.src[l * 5 + 3] = upd_w1 + (size_t)l * 256 * 128 + 128 * 128;
    wp.src[l * 5 + 4] = upd_w2 + (size_t)l * 128 * 128;
  }
  wp.src[20] = head_w1;
  wp.src[21] = lin_w;

  int ngrid = (N + 63) / 64;
  int egrid = (E + 127) / 128;

  hipMemsetAsync(cnti, 0, Nr * 4, stream);
  hipMemsetAsync(tmpc, 0, Nr * 4, stream);
  wconv_kernel<<<dim3(64, 22), 256, 0, stream>>>(wp, wtb, wlin);
  count_int_kernel<<<(E + 255) / 256, 256, 0, stream>>>(dst, cnti, E);
  prefix_kernel<<<1, 1024, 0, stream>>>(cnti, rowp, N);
  inv_kernel<<<(N + 255) / 256, 256, 0, stream>>>(cnti, invf, N);
  scatter_kernel<<<(E + 255) / 256, 256, 0, stream>>>(src, dst, (const float4*)ea,
                                                      rowp, tmpc, srcs, dsts, eas, E);
  lin_hw_kernel<<<ngrid, 256, 0, stream>>>(x, wlin, lin_b, wtb, msg_b1, h, hwb, N);

  for (int l = 0; l < 4; ++l) {
    const ushort* mw2t  = wtb + (size_t)(l * 5 + 1) * 16384;
    const ushort* wu1at = wtb + (size_t)(l * 5 + 2) * 16384;
    const ushort* wu1bt = wtb + (size_t)(l * 5 + 3) * 16384;
    const ushort* wu2t  = wtb + (size_t)(l * 5 + 4) * 16384;
    const float*  wea   = msg_w1 + (size_t)l * 132 * 128 + 128 * 128;
    int last = (l == 3);
    const ushort* Wn = last ? (wtb + (size_t)20 * 16384)
                            : (wtb + (size_t)((l + 1) * 5 + 0) * 16384);
    const float* bn = last ? head_b1 : (msg_b1 + (l + 1) * 128);

    hipMemsetAsync(agg, 0, NH * sizeof(float), stream);
    edge_kernel_v3<<<egrid, 256, 0, stream>>>(hwb, eas, srcs, dsts, mw2t, wea,
                                              msg_b2 + l * 128, agg, E);
    fused_update<<<ngrid, 256, 0, stream>>>(h, agg, invf, wu1at, wu1bt, wu2t,
                                            upd_b1 + l * 128, upd_b2 + l * 128,
                                            Wn, bn, h, last ? nullptr : hwb,
                                            head_w2, head_b2, out, N, last);
  }
}